// Round 2
// baseline (105.696 us; speedup 1.0000x reference)
//
#include <hip/hip_runtime.h>

// Inverse 2D Haar wavelet:
//   in : (B=16, 4*CH=256, H=128, W=128) f32
//   out: (B=16, CH=64,   2H=256, 2W=256) f32
// out[b,c,2h+0,2w+0] = (LL+LH+HL+HH)*0.5
// out[b,c,2h+0,2w+1] = (LL+LH-HL-HH)*0.5
// out[b,c,2h+1,2w+0] = (LL-LH+HL-HH)*0.5
// out[b,c,2h+1,2w+1] = (LL-LH-HL+HH)*0.5

__global__ __launch_bounds__(256) void iwt2d_kernel(const float* __restrict__ x,
                                                    float* __restrict__ out) {
    constexpr int B = 16, CH = 64, H = 128, W = 128;
    constexpr int WQ = W / 4;                       // 32 float4 groups per row
    const int t = blockIdx.x * blockDim.x + threadIdx.x;
    // total threads = B*CH*H*WQ = 16*64*128*32 = 4,194,304 (grid sized exactly)
    const int wq = t & (WQ - 1);
    const int h  = (t >> 5) & (H - 1);
    const int c  = (t >> 12) & (CH - 1);
    const int b  = t >> 18;
    if (b >= B) return;

    const size_t plane   = (size_t)H * W;           // 16384
    const size_t in_boff = (size_t)b * (4 * CH) * plane;
    const float* base = x + in_boff + (size_t)c * plane + (size_t)h * W + (size_t)wq * 4;

    const float4 ll = *(const float4*)(base);
    const float4 lh = *(const float4*)(base +  (size_t)CH       * plane);
    const float4 hl = *(const float4*)(base + ((size_t)CH * 2)  * plane);
    const float4 hh = *(const float4*)(base + ((size_t)CH * 3)  * plane);

    float4 a, bb, cc, dd;
    a.x  = (ll.x + lh.x + hl.x + hh.x) * 0.5f;
    a.y  = (ll.y + lh.y + hl.y + hh.y) * 0.5f;
    a.z  = (ll.z + lh.z + hl.z + hh.z) * 0.5f;
    a.w  = (ll.w + lh.w + hl.w + hh.w) * 0.5f;
    bb.x = (ll.x + lh.x - hl.x - hh.x) * 0.5f;
    bb.y = (ll.y + lh.y - hl.y - hh.y) * 0.5f;
    bb.z = (ll.z + lh.z - hl.z - hh.z) * 0.5f;
    bb.w = (ll.w + lh.w - hl.w - hh.w) * 0.5f;
    cc.x = (ll.x - lh.x + hl.x - hh.x) * 0.5f;
    cc.y = (ll.y - lh.y + hl.y - hh.y) * 0.5f;
    cc.z = (ll.z - lh.z + hl.z - hh.z) * 0.5f;
    cc.w = (ll.w - lh.w + hl.w - hh.w) * 0.5f;
    dd.x = (ll.x - lh.x - hl.x + hh.x) * 0.5f;
    dd.y = (ll.y - lh.y - hl.y + hh.y) * 0.5f;
    dd.z = (ll.z - lh.z - hl.z + hh.z) * 0.5f;
    dd.w = (ll.w - lh.w - hl.w + hh.w) * 0.5f;

    // output rows 2h and 2h+1; 8 consecutive floats per thread per row
    const size_t oW = 2 * W;                        // 256
    const size_t oplane = (size_t)(2 * H) * oW;     // 131072
    float* orow0 = out + (size_t)b * CH * oplane + (size_t)c * oplane
                       + (size_t)(2 * h) * oW + (size_t)wq * 8;
    float* orow1 = orow0 + oW;

    float4 t0, t1, u0, u1;
    t0.x = a.x;  t0.y = bb.x; t0.z = a.y;  t0.w = bb.y;
    t1.x = a.z;  t1.y = bb.z; t1.z = a.w;  t1.w = bb.w;
    u0.x = cc.x; u0.y = dd.x; u0.z = cc.y; u0.w = dd.y;
    u1.x = cc.z; u1.y = dd.z; u1.z = cc.w; u1.w = dd.w;

    *(float4*)(orow0)     = t0;
    *(float4*)(orow0 + 4) = t1;
    *(float4*)(orow1)     = u0;
    *(float4*)(orow1 + 4) = u1;
}

extern "C" void kernel_launch(void* const* d_in, const int* in_sizes, int n_in,
                              void* d_out, int out_size, void* d_ws, size_t ws_size,
                              hipStream_t stream) {
    const float* x = (const float*)d_in[0];
    float* out = (float*)d_out;
    constexpr int total_threads = 16 * 64 * 128 * 32;   // 4,194,304
    constexpr int block = 256;
    constexpr int grid = total_threads / block;          // 16384
    iwt2d_kernel<<<grid, block, 0, stream>>>(x, out);
}